// Round 1
// 1983.632 us; speedup vs baseline: 1.0816x; 1.0816x over previous
//
#include <hip/hip_runtime.h>
#include <hip/hip_bf16.h>
#include <stdint.h>

// Problem constants: B=4, S=512, E=768, H=12, D=64, L=12, FF=3072, M = B*S = 2048
#define LAYERS 12
#define M_ROWS 2048
#define E_DIM 768
#define FF_DIM 3072
#define QKV_DIM 2304
#define SCALE_INV 0.036084391824351615f  // 1/sqrt(768)

typedef __hip_bfloat16 bf16;
typedef __attribute__((ext_vector_type(8))) __bf16 bf16x8;
typedef __attribute__((ext_vector_type(4))) float f32x4;

__device__ __forceinline__ float bf2f(bf16 v) { return __bfloat162float(v); }
__device__ __forceinline__ bf16 f2bf(float v) { return __float2bfloat16(v); }

__device__ __forceinline__ float gelu_f(float x) {
  return 0.5f * x * (1.0f + erff(x * 0.70710678118654752f));
}

// async global->LDS, 16 bytes per lane. LDS dest must be wave-uniform base;
// HW adds lane*16. (learn_hip m97 pattern)
__device__ __forceinline__ void async16(const bf16* g, bf16* l) {
  __builtin_amdgcn_global_load_lds(
      (const __attribute__((address_space(1))) void*)g,
      (__attribute__((address_space(3))) void*)l, 16, 0, 0);
}

// ---------------------------------------------------------------------------
// Batched weight transpose+convert: fp32 [K][N] -> bf16 [N][K] for the 4
// weight matrices of one layer. 32x32 tiles via LDS.
// ---------------------------------------------------------------------------
__global__ __launch_bounds__(256) void transpose_k(
    const float* __restrict__ w0, const float* __restrict__ w1,
    const float* __restrict__ w2, const float* __restrict__ w3,
    bf16* __restrict__ t0, bf16* __restrict__ t1,
    bf16* __restrict__ t2, bf16* __restrict__ t3)
{
  __shared__ float T[32][33];
  int bid = blockIdx.x;
  const float* src; bf16* dst; int K, N, tile;
  if (bid < 1728)      { src = w0; dst = t0; K = 768;  N = 2304; tile = bid; }
  else if (bid < 2304) { src = w1; dst = t1; K = 768;  N = 768;  tile = bid - 1728; }
  else if (bid < 4608) { src = w2; dst = t2; K = 768;  N = 3072; tile = bid - 2304; }
  else                 { src = w3; dst = t3; K = 3072; N = 768;  tile = bid - 4608; }
  int tilesN = N >> 5;
  int tk = tile / tilesN;
  int tn = tile - tk * tilesN;
  int tx = threadIdx.x & 31, ty = threadIdx.x >> 5;
  int k0 = tk << 5, n0 = tn << 5;
#pragma unroll
  for (int i = 0; i < 4; i++)
    T[ty + i * 8][tx] = src[(size_t)(k0 + ty + i * 8) * N + n0 + tx];
  __syncthreads();
#pragma unroll
  for (int i = 0; i < 4; i++)
    dst[(size_t)(n0 + ty + i * 8) * K + k0 + tx] = f2bf(T[tx][ty + i * 8]);
}

// ---------------------------------------------------------------------------
// LayerNorm over last dim (768). One block (256 thr) per row.
// NPART=2: input is two fp32 partial buffers (split-K GEMM output), summed
// before stats — keeps split-K deterministic with no atomics.
// ---------------------------------------------------------------------------
template<int OUT_BF16, int NADD, int NPART>
__global__ __launch_bounds__(256) void ln_k(
    const float* __restrict__ in, const float* __restrict__ gamma,
    const float* __restrict__ beta, const float* __restrict__ add0,
    const float* __restrict__ add1, void* __restrict__ outp)
{
  int row = blockIdx.x, tid = threadIdx.x;
  size_t rb = (size_t)row * 768;
  float v[3]; float s = 0.f, sq = 0.f;
#pragma unroll
  for (int j = 0; j < 3; j++) {
    int c = tid + j * 256;
    float x = in[rb + c];
    if (NPART == 2) x += in[(size_t)M_ROWS * 768 + rb + c];
    v[j] = x;
    s += x; sq += x * x;
  }
#pragma unroll
  for (int off = 32; off; off >>= 1) {
    s += __shfl_xor(s, off);
    sq += __shfl_xor(sq, off);
  }
  __shared__ float red[8];
  int wv = tid >> 6;
  if ((tid & 63) == 0) { red[wv] = s; red[4 + wv] = sq; }
  __syncthreads();
  s  = red[0] + red[1] + red[2] + red[3];
  sq = red[4] + red[5] + red[6] + red[7];
  float mean = s * (1.0f / 768.0f);
  float var  = sq * (1.0f / 768.0f) - mean * mean;
  float rstd = rsqrtf(var + 1e-5f);
#pragma unroll
  for (int j = 0; j < 3; j++) {
    int c = tid + j * 256;
    float val = (v[j] - mean) * rstd * gamma[c] + beta[c];
    if (NADD >= 1) val += add0[rb + c];
    if (NADD >= 2) val += add1[rb + c];
    if (OUT_BF16) ((bf16*)outp)[rb + c] = f2bf(val);
    else          ((float*)outp)[rb + c] = val;
  }
}

// ---------------------------------------------------------------------------
// bf16 MFMA GEMM, 128x64 tile, 256 threads = 4 waves; wave w owns rows
// [w*32, w*32+32) x all 64 cols -> acc[2][4] of 16x16 frags, 8 MFMA/K-step.
// Staging: global_load_lds dwordx4 (3 issues/thread/K-step), double-buffered
// LDS, single __syncthreads per K-step (T3 minimal 2-phase recipe).
// OUT_MODE: 0 = fp32 out (supports NSPLIT partials), 1 = bf16, 2 = bf16+GELU,
//           3 = split-QKV out; q,k as [B][H][S][D], v TRANSPOSED [B][H][D][S].
// NSPLIT>1: blockIdx.y = K-chunk; partial written at Cout + sp*M*N (fp32).
// ---------------------------------------------------------------------------
template<int OUT_MODE, int NSPLIT>
__global__ __launch_bounds__(256) void gemm2_k(
    const bf16* __restrict__ A, const bf16* __restrict__ BT,
    const float* __restrict__ bias, void* __restrict__ Cout,
    bf16* __restrict__ qo, bf16* __restrict__ ko, bf16* __restrict__ vo,
    int N, int K)
{
  __shared__ __align__(16) bf16 Als[2][128 * 32];
  __shared__ __align__(16) bf16 Bls[2][64 * 32];
  int tid = threadIdx.x;
  int lane = tid & 63, w = tid >> 6;
  int l15 = lane & 15, l4 = lane >> 4;
  int Nt = N >> 6;
  int mt = blockIdx.x / Nt, ntile = blockIdx.x - mt * Nt;
  int m0 = mt << 7, n0 = ntile << 6;
  int sp = (NSPLIT > 1) ? blockIdx.y : 0;
  int Kc = K / NSPLIT;
  int kbeg = sp * Kc, kend = kbeg + Kc;
  const bf16* Ap = A + (size_t)m0 * K;
  const bf16* Bp = BT + (size_t)n0 * K;
  int ar = tid >> 2;            // source row within tile (0..63)
  int ac = (tid & 3) * 8;       // source k-offset (x8 elems = 16B)

  f32x4 acc[2][4] = {};

  // prologue: stage K-step 0 into buffer 0
  async16(Ap + (size_t)ar * K + kbeg + ac,        &Als[0][w * 512]);
  async16(Ap + (size_t)(ar + 64) * K + kbeg + ac, &Als[0][2048 + w * 512]);
  async16(Bp + (size_t)ar * K + kbeg + ac,        &Bls[0][w * 512]);
  __syncthreads();   // drains vmcnt(0): buf0 ready

  int cur = 0;
  for (int k0 = kbeg; k0 < kend; k0 += 32) {
    // issue next tile's loads first — they fly while we do MFMA
    if (k0 + 32 < kend) {
      int kn = k0 + 32;
      async16(Ap + (size_t)ar * K + kn + ac,        &Als[cur ^ 1][w * 512]);
      async16(Ap + (size_t)(ar + 64) * K + kn + ac, &Als[cur ^ 1][2048 + w * 512]);
      async16(Bp + (size_t)ar * K + kn + ac,        &Bls[cur ^ 1][w * 512]);
    }
    bf16x8 af[2], bfr[4];
#pragma unroll
    for (int i = 0; i < 2; i++)
      af[i] = *(const bf16x8*)&Als[cur][(w * 32 + i * 16 + l15) * 32 + l4 * 8];
#pragma unroll
    for (int j = 0; j < 4; j++)
      bfr[j] = *(const bf16x8*)&Bls[cur][(j * 16 + l15) * 32 + l4 * 8];
#pragma unroll
    for (int i = 0; i < 2; i++)
#pragma unroll
      for (int j = 0; j < 4; j++)
        acc[i][j] = __builtin_amdgcn_mfma_f32_16x16x32_bf16(af[i], bfr[j], acc[i][j], 0, 0, 0);
    __syncthreads();   // drains vmcnt(0) + lgkmcnt: next buffer ready, reads done
    cur ^= 1;
  }

  // epilogue
#pragma unroll
  for (int i = 0; i < 2; i++) {
    int mbase = m0 + w * 32 + i * 16 + (l4 << 2);
#pragma unroll
    for (int j = 0; j < 4; j++) {
      int n = n0 + j * 16 + l15;
      float bvs = (NSPLIT == 1 || sp == 0) ? bias[n] : 0.0f;
      if (OUT_MODE == 3) {
        int h = n / 192;
        int rm = n - h * 192;
        int d = rm / 3;
        int t = rm - d * 3;
#pragma unroll
        for (int rg = 0; rg < 4; rg++) {
          int m = mbase + rg;
          float val = acc[i][j][rg] + bvs;
          int b = m >> 9, sIdx = m & 511;
          int bh = b * 12 + h;
          if (t == 2)
            vo[(size_t)((bh << 6) + d) * 512 + sIdx] = f2bf(val);       // [B][H][D][S]
          else {
            bf16* dsts = (t == 0) ? qo : ko;
            dsts[(size_t)((bh << 9) + sIdx) * 64 + d] = f2bf(val);      // [B][H][S][D]
          }
        }
      } else {
#pragma unroll
        for (int rg = 0; rg < 4; rg++) {
          int m = mbase + rg;
          float val = acc[i][j][rg] + bvs;
          if (OUT_MODE == 0)
            ((float*)Cout)[(size_t)sp * M_ROWS * N + (size_t)m * N + n] = val;
          else if (OUT_MODE == 1)
            ((bf16*)Cout)[(size_t)m * N + n] = f2bf(val);
          else
            ((bf16*)Cout)[(size_t)m * N + n] = f2bf(gelu_f(val));
        }
      }
    }
  }
}

// ---------------------------------------------------------------------------
// MFMA flash attention. Block = one (b,h) x 64 query rows; 4 waves x 16 rows.
// q,k: bf16 [B][H][S][D];  vT: bf16 [B][H][D][S];  o: bf16 [B*S][768].
// att = softmax(q.k) / sqrt(768)  (scale after softmax — faithful).
// Online softmax over 8 key-tiles of 64.
// ---------------------------------------------------------------------------
#define PSTR 80   // P staging row stride (bf16 elems): 160B rows -> 4-way max conflict
__global__ __launch_bounds__(256) void attn_k(
    const bf16* __restrict__ q, const bf16* __restrict__ k,
    const bf16* __restrict__ vT, bf16* __restrict__ o)
{
  __shared__ __align__(16) bf16 Kls[64 * 64];        // [key][d]
  __shared__ __align__(16) bf16 Vls[64 * 64];        // [d][key]
  __shared__ __align__(16) bf16 Pls[4][16 * PSTR];   // per-wave P transpose buf
  int tid = threadIdx.x;
  int lane = tid & 63, w = tid >> 6;
  int l15 = lane & 15, l4 = lane >> 4;
  int qt = blockIdx.x & 7;
  int bh = blockIdx.x >> 3;
  size_t base = (size_t)bh * 32768;    // 512*64

  // Q A-fragments, loaded once from global (contiguous d)
  const bf16* qrowp = q + base + (size_t)(qt * 64 + w * 16 + l15) * 64 + l4 * 8;
  bf16x8 qf0 = *(const bf16x8*)qrowp;
  bf16x8 qf1 = *(const bf16x8*)(qrowp + 32);

  float mrow[4] = {-1e30f, -1e30f, -1e30f, -1e30f};
  float lsum[4] = {0.f, 0.f, 0.f, 0.f};
  f32x4 Oacc[4] = {};
  const f32x4 zed = {0.f, 0.f, 0.f, 0.f};
  bf16* pw = &Pls[w][0];

  for (int kt = 0; kt < 8; kt++) {
    __syncthreads();   // previous iter's LDS reads done before overwrite
    // stage K tile [64][64] and VT tile [64 d][64 kk]
#pragma unroll
    for (int rep = 0; rep < 2; rep++) {
      int c = tid + rep * 256;
      int row = c >> 3, col8 = (c & 7) * 8;
      *(uint4*)&Kls[row * 64 + col8] =
          *(const uint4*)(k + base + (size_t)(kt * 64 + row) * 64 + col8);
      *(uint4*)&Vls[row * 64 + col8] =
          *(const uint4*)(vT + base + (size_t)row * 512 + kt * 64 + col8);
    }
    __syncthreads();
    // e = Q @ K^T for this wave's 16 rows x 64 keys (4 C-tiles)
    f32x4 e[4];
#pragma unroll
    for (int jt = 0; jt < 4; jt++) {
      bf16x8 kf0 = *(const bf16x8*)&Kls[(jt * 16 + l15) * 64 + l4 * 8];
      bf16x8 kf1 = *(const bf16x8*)&Kls[(jt * 16 + l15) * 64 + l4 * 8 + 32];
      e[jt] = __builtin_amdgcn_mfma_f32_16x16x32_bf16(qf0, kf0, zed, 0, 0, 0);
      e[jt] = __builtin_amdgcn_mfma_f32_16x16x32_bf16(qf1, kf1, e[jt], 0, 0, 0);
    }
    // online softmax stats; row = l4*4+reg, shared by the 16 lanes with same l4
    float al[4];
#pragma unroll
    for (int rg = 0; rg < 4; rg++) {
      float mn = fmaxf(fmaxf(e[0][rg], e[1][rg]), fmaxf(e[2][rg], e[3][rg]));
#pragma unroll
      for (int off = 1; off < 16; off <<= 1) mn = fmaxf(mn, __shfl_xor(mn, off));
      float mnew = fmaxf(mrow[rg], mn);
      al[rg] = __expf(mrow[rg] - mnew);
      mrow[rg] = mnew;
    }
    float rs[4] = {0.f, 0.f, 0.f, 0.f};
#pragma unroll
    for (int jt = 0; jt < 4; jt++)
#pragma unroll
      for (int rg = 0; rg < 4; rg++) {
        float p = __expf(e[jt][rg] - mrow[rg]);
        rs[rg] += p;
        pw[(l4 * 4 + rg) * PSTR + jt * 16 + l15] = f2bf(p);
      }
#pragma unroll
    for (int rg = 0; rg < 4; rg++) {
#pragma unroll
      for (int off = 1; off < 16; off <<= 1) rs[rg] += __shfl_xor(rs[rg], off);
      lsum[rg] = lsum[rg] * al[rg] + rs[rg];
    }
#pragma unroll
    for (int dt = 0; dt < 4; dt++)
#pragma unroll
      for (int rg = 0; rg < 4; rg++) Oacc[dt][rg] *= al[rg];
    // P back out in A-layout (within-wave LDS round trip)
    bf16x8 pf0 = *(const bf16x8*)&pw[l15 * PSTR + l4 * 8];
    bf16x8 pf1 = *(const bf16x8*)&pw[l15 * PSTR + l4 * 8 + 32];
    // O += P @ V  (B-operand from VT: n=d, k=key, contiguous key)
#pragma unroll
    for (int dt = 0; dt < 4; dt++) {
      bf16x8 vf0 = *(const bf16x8*)&Vls[(dt * 16 + l15) * 64 + l4 * 8];
      bf16x8 vf1 = *(const bf16x8*)&Vls[(dt * 16 + l15) * 64 + l4 * 8 + 32];
      Oacc[dt] = __builtin_amdgcn_mfma_f32_16x16x32_bf16(pf0, vf0, Oacc[dt], 0, 0, 0);
      Oacc[dt] = __builtin_amdgcn_mfma_f32_16x16x32_bf16(pf1, vf1, Oacc[dt], 0, 0, 0);
    }
  }
  // epilogue: O[q][d] * SCALE_INV / l  -> o[b*512+s][h*64+d]
  int b = bh / 12, h = bh - b * 12;
#pragma unroll
  for (int rg = 0; rg < 4; rg++) {
    int qrow = qt * 64 + w * 16 + l4 * 4 + rg;
    float inv = SCALE_INV / lsum[rg];
    size_t rowoff = (size_t)(b * 512 + qrow) * 768 + h * 64;
#pragma unroll
    for (int dt = 0; dt < 4; dt++)
      o[rowoff + dt * 16 + l15] = f2bf(Oacc[dt][rg] * inv);
  }
}

// ---------------------------------------------------------------------------
extern "C" void kernel_launch(void* const* d_in, const int* in_sizes, int n_in,
                              void* d_out, int out_size, void* d_ws, size_t ws_size,
                              hipStream_t stream)
{
  const float* x    = (const float*)d_in[0];
  const float* Wqkv = (const float*)d_in[1];
  const float* bqkv = (const float*)d_in[2];
  const float* Wp   = (const float*)d_in[3];
  const float* bp   = (const float*)d_in[4];
  const float* W1   = (const float*)d_in[5];
  const float* b1   = (const float*)d_in[6];
  const float* W2   = (const float*)d_in[7];
  const float* b2   = (const float*)d_in[8];
  const float* g1  = (const float*)d_in[9];
  const float* be1 = (const float*)d_in[10];
  const float* g2  = (const float*)d_in[11];
  const float* be2 = (const float*)d_in[12];
  const float* g3  = (const float*)d_in[13];
  const float* be3 = (const float*)d_in[14];
  const float* g4  = (const float*)d_in[15];
  const float* be4 = (const float*)d_in[16];
  float* xout = (float*)d_out;

  char* ws = (char*)d_ws;
  size_t off = 0;
  auto alloc = [&](size_t bytes) -> char* {
    char* p = ws + off;
    off += (bytes + 255) & ~(size_t)255;
    return p;
  };
  const size_t NTOK = (size_t)M_ROWS * E_DIM;
  bf16*  qb  = (bf16*)alloc(NTOK * 2);
  bf16*  kb  = (bf16*)alloc(NTOK * 2);
  bf16*  vb  = (bf16*)alloc(NTOK * 2);   // holds V^T [B][H][D][S]
  bf16*  hb  = (bf16*)alloc(NTOK * 2);
  bf16*  ob  = (bf16*)alloc(NTOK * 2);
  bf16*  f1b = (bf16*)alloc((size_t)M_ROWS * FF_DIM * 2);
  float* tmp = (float*)alloc(NTOK * 4 * 2);   // 2 split-K fp32 partials
  float* r1  = (float*)alloc(NTOK * 4);
  bf16*  tq  = (bf16*)alloc((size_t)768 * 2304 * 2);
  bf16*  tp  = (bf16*)alloc((size_t)768 * 768 * 2);
  bf16*  t1  = (bf16*)alloc((size_t)768 * 3072 * 2);
  bf16*  t2  = (bf16*)alloc((size_t)3072 * 768 * 2);
  if (off > ws_size) {
    hipMemsetAsync(d_out, 0x7f, (size_t)out_size * 4, stream);
    return;
  }

  hipMemcpyAsync(d_out, x, (size_t)out_size * 4, hipMemcpyDeviceToDevice, stream);

  for (int l = 0; l < LAYERS; l++) {
    const float* wq  = Wqkv + (size_t)l * 768 * 2304;
    const float* wp_ = Wp   + (size_t)l * 768 * 768;
    const float* w1_ = W1   + (size_t)l * 768 * 3072;
    const float* w2_ = W2   + (size_t)l * 3072 * 768;

    transpose_k<<<6912, 256, 0, stream>>>(wq, wp_, w1_, w2_, tq, tp, t1, t2);

    ln_k<1, 0, 1><<<2048, 256, 0, stream>>>(xout, g1 + l * 768, be1 + l * 768,
                                            nullptr, nullptr, hb);
    // QKV: M=2048,N=2304,K=768 -> 16x36 = 576 blocks
    gemm2_k<3, 1><<<dim3(16 * 36, 1), 256, 0, stream>>>(
        hb, tq, bqkv + (size_t)l * 2304, nullptr, qb, kb, vb, 2304, 768);
    attn_k<<<384, 256, 0, stream>>>(qb, kb, vb, ob);
    // proj: M=2048,N=768,K=768 split-K 2 -> 16x12x2 = 384 blocks, fp32 partials
    gemm2_k<0, 2><<<dim3(16 * 12, 2), 256, 0, stream>>>(
        ob, tp, bp + (size_t)l * 768, tmp, nullptr, nullptr, nullptr, 768, 768);
    ln_k<0, 1, 2><<<2048, 256, 0, stream>>>(tmp, g2 + l * 768, be2 + l * 768,
                                            xout, nullptr, r1);
    ln_k<1, 0, 1><<<2048, 256, 0, stream>>>(r1, g3 + l * 768, be3 + l * 768,
                                            nullptr, nullptr, hb);
    // FF1: M=2048,N=3072,K=768 -> 16x48 = 768 blocks
    gemm2_k<2, 1><<<dim3(16 * 48, 1), 256, 0, stream>>>(
        hb, t1, b1 + (size_t)l * 3072, f1b, nullptr, nullptr, nullptr, 3072, 768);
    // FF2: M=2048,N=768,K=3072 split-K 2 -> 384 blocks, fp32 partials
    gemm2_k<0, 2><<<dim3(16 * 12, 2), 256, 0, stream>>>(
        f1b, t2, b2 + (size_t)l * 768, tmp, nullptr, nullptr, nullptr, 768, 3072);
    ln_k<0, 2, 2><<<2048, 256, 0, stream>>>(tmp, g4 + l * 768, be4 + l * 768,
                                            r1, xout, xout);
  }
}